// Round 1
// 108.403 us; speedup vs baseline: 1.1330x; 1.1330x over previous
//
#include <hip/hip_runtime.h>

#define RR 4
#define NS 17
#define BB 4
#define CC 128
#define HH 96
#define WW 160
#define HWSZ (HH * WW)

// Block: 32 (w) x 8 (h); each thread owns ONE pixel.
// Pixel tile: 8 rows x 32 cols. LDS tgt tile: 16 x 40 (halo R=4 each side),
// vectorized over 4 consecutive channels (float4 per element).
#define TW 32
#define HTILE 8
#define TROWS (HTILE + 2 * RR)   // 16
#define TCOLS (TW + 2 * RR)      // 40
#define TILE_E (TROWS * TCOLS)   // 640 float4 elements = 10240 B
#define CCHUNK 32                // channels per block
#define NCHUNK (CC / CCHUNK)     // 4 (atomic-accumulated)
#define CG 4                     // channels per group (float4)
#define NG (CCHUNK / CG)         // 8 groups per block
#define NSPX (WW / TW)           // 5
#define NSPY (HH / HTILE)        // 12
#define NSP (NSPX * NSPY)        // 60 spatial tiles
#define NWG (NSP * BB * NCHUNK)  // 960 workgroups
#define NXCD 8
#define WGPX (NWG / NXCD)        // 120 (exact)

#define FMA4(a, t) \
    (a) = fmaf(svx, (t).x, fmaf(svy, (t).y, fmaf(svz, (t).z, fmaf(svw, (t).w, (a)))))

__global__ __launch_bounds__(256, 4)
void cost_volume_kernel(const float* __restrict__ src,
                        const float* __restrict__ tgt,
                        float* __restrict__ out) {
    __shared__ float4 tile[TILE_E];

    const int x   = threadIdx.x;          // 0..31
    const int hg  = threadIdx.y;          // 0..7
    const int tid = hg * TW + x;          // 0..255

    // XCD-aware bijective swizzle: HW round-robins consecutive dispatch ids
    // across 8 XCDs; remap so each XCD gets a contiguous work range
    // (spatial-major -> halo re-reads hit the same XCD's L2).
    const int flat = blockIdx.x;                      // dispatch id, 0..959
    const int wg   = (flat & (NXCD - 1)) * WGPX + (flat >> 3);
    const int sp   = wg % NSP;                        // spatial tile (x-fastest)
    const int z    = wg / NSP;                        // b*? + channel chunk
    const int wx   = sp % NSPX;
    const int wy   = sp / NSPX;

    const int w0 = wx * TW;
    const int h0 = wy * HTILE;
    const int b  = z & 3;
    const int c0 = (z >> 2) * CCHUNK;

    const int w = w0 + x;                 // always < WW
    const int h = h0 + hg;                // always < HH

    const float* tgt_b = tgt + (size_t)(b * CC + c0) * HWSZ;
    const float* src_p = src + (size_t)(b * CC + c0) * HWSZ + h * WW + w;

    // --- precompute staging slots (invariant across channel groups) ---
    int  sOff[3];
    bool sVal[3];
#pragma unroll
    for (int k = 0; k < 3; ++k) {
        const int idx = tid + k * 256;
        const int r   = idx / TCOLS;
        const int col = idx - r * TCOLS;
        const int gr  = h0 - RR + r;
        const int gc  = w0 - RR + col;
        sVal[k] = (idx < TILE_E) && gr >= 0 && gr < HH && gc >= 0 && gc < WW;
        sOff[k] = gr * WW + gc;
    }

    float4 pre[3];                        // tgt tile prefetch (3 f4/thread)
    float  sv4[4];                        // src prefetch (4 channels)

    auto fetch = [&](int g) {
        const float* t = tgt_b + (size_t)(g * CG) * HWSZ;
#pragma unroll
        for (int k = 0; k < 3; ++k) {
            float4 v = make_float4(0.f, 0.f, 0.f, 0.f);
            if (sVal[k]) {
                const float* p = t + sOff[k];
                v.x = p[0];
                v.y = p[HWSZ];
                v.z = p[2 * HWSZ];
                v.w = p[3 * HWSZ];
            }
            pre[k] = v;
        }
        const float* s = src_p + (size_t)(g * CG) * HWSZ;
#pragma unroll
        for (int k = 0; k < 4; ++k) sv4[k] = s[k * HWSZ];
    };

    float acc[NS];
#pragma unroll
    for (int s = 0; s < NS; ++s) acc[s] = 0.f;

    fetch(0);
    const int base = (RR + hg) * TCOLS + (RR + x);

    for (int g = 0; g < NG; ++g) {
        // write staged regs to LDS (b128 writes, conflict-balanced)
        tile[tid]       = pre[0];
        tile[tid + 256] = pre[1];
        if (tid + 512 < TILE_E) tile[tid + 512] = pre[2];
        const float svx = sv4[0], svy = sv4[1], svz = sv4[2], svw = sv4[3];
        __syncthreads();

        // prefetch next group while computing this one
        if (g + 1 < NG) fetch(g + 1);

        // compute: 17 ds_read_b128 + 68 FMAs (4 channels at once)
        {
            float4 tc = tile[base];
            FMA4(acc[0], tc);
#pragma unroll
            for (int off = 1; off <= RR; ++off) {
                float4 tu = tile[base - off * TCOLS];
                float4 td = tile[base + off * TCOLS];
                float4 tl = tile[base - off];
                float4 tr = tile[base + off];
                FMA4(acc[4 * off - 3], tu);
                FMA4(acc[4 * off - 2], td);
                FMA4(acc[4 * off - 1], tl);
                FMA4(acc[4 * off    ], tr);
            }
        }
        __syncthreads();
    }

    // epilogue: atomic accumulate (4 channel-chunks race per output)
    float* op = out + (((size_t)b * NS) * HH + h) * WW + w;
#pragma unroll
    for (int s = 0; s < NS; ++s) {
        atomicAdd(op + (size_t)s * HWSZ, acc[s]);
    }
}

extern "C" void kernel_launch(void* const* d_in, const int* in_sizes, int n_in,
                              void* d_out, int out_size, void* d_ws, size_t ws_size,
                              hipStream_t stream) {
    const float* src = (const float*)d_in[0];
    const float* tgt = (const float*)d_in[1];
    float* out = (float*)d_out;

    // d_out is poisoned before every launch; we accumulate atomically -> zero it
    hipMemsetAsync(out, 0, (size_t)out_size * sizeof(float), stream);

    dim3 block(TW, 8, 1);      // 256 threads
    dim3 grid(NWG, 1, 1);      // 960 blocks
    cost_volume_kernel<<<grid, block, 0, stream>>>(src, tgt, out);
}